// Round 9
// baseline (548.792 us; speedup 1.0000x reference)
//
#include <hip/hip_runtime.h>
#include <math.h>

#define N_NODES 50000
#define N_EDGES 300000
#define IN_DIM 64
#define H 256
#define LAYERS 4
#define NB 181
#define NGRAPH 64
#define EE (N_EDGES + N_NODES)
#define NEG_SLOPE 0.2f
#define LN_EPS 1e-5f

typedef unsigned short u16;
typedef __attribute__((ext_vector_type(8))) _Float16 half8;
typedef __attribute__((ext_vector_type(4))) float floatx4;
typedef __attribute__((ext_vector_type(2))) _Float16 h2;

__device__ __forceinline__ u16 f2h(float f) {
  _Float16 h = (_Float16)f;
  return __builtin_bit_cast(u16, h);
}
__device__ __forceinline__ float h2f(u16 b) {
  return (float)__builtin_bit_cast(_Float16, b);
}
__device__ __forceinline__ h2 u2h2(unsigned int u) {
  return __builtin_bit_cast(h2, u);
}
__device__ __forceinline__ float fdot2f(h2 a, h2 b, float c) {
  typedef __attribute__((ext_vector_type(2))) __fp16 hb;
  return __builtin_amdgcn_fdot2(__builtin_bit_cast(hb, a),
                                __builtin_bit_cast(hb, b), c, false);
}

__device__ __forceinline__ float wave_reduce_sum(float v) {
  #pragma unroll
  for (int off = 32; off > 0; off >>= 1) v += __shfl_xor(v, off, 64);
  return v;
}

// 5-stage reduce within a 32-lane half (offsets <32 never cross halves)
__device__ __forceinline__ float half_reduce_sum(float v) {
  v += __shfl_xor(v, 1, 64);
  v += __shfl_xor(v, 2, 64);
  v += __shfl_xor(v, 4, 64);
  v += __shfl_xor(v, 8, 64);
  v += __shfl_xor(v, 16, 64);
  return v;
}

// ---------------- weight casts (Wg1, Wl, Wr) ----------------
__global__ void cast_weights_kernel(
    const float* __restrict__ Wg1,
    const float* __restrict__ Wl, const float* __restrict__ Wr,
    u16* __restrict__ wg1_h, u16* __restrict__ wl_h, u16* __restrict__ wr_h)
{
  int i = blockIdx.x * 256 + threadIdx.x;
  int which = blockIdx.y;
  const float* s; u16* dd; int n4;
  if (which == 0)      { s = Wg1;  dd = wg1_h; n4 = H * H / 4; }
  else if (which == 1) { s = Wl;   dd = wl_h;  n4 = LAYERS * H * H / 4; }
  else                 { s = Wr;   dd = wr_h;  n4 = LAYERS * H * H / 4; }
  if (i < n4) {
    float4 f = ((const float4*)s)[i];
    ushort4 o;
    o.x = f2h(f.x); o.y = f2h(f.y); o.z = f2h(f.z); o.w = f2h(f.w);
    ((ushort4*)dd)[i] = o;
  }
}

// ---------------- CSR build + gate/graph-bounds init (merged) ----------------
__global__ void init_kernel(int* __restrict__ cnt,
                            float* __restrict__ gate, const float* __restrict__ bg2,
                            const int* __restrict__ batch,
                            int* __restrict__ gstart, int* __restrict__ gend) {
  int i = blockIdx.x * 256 + threadIdx.x;
  if (i < N_NODES) {
    cnt[i] = 1;  // self loop
    gate[i] = bg2[0];
    int b = batch[i];
    if (i == 0 || batch[i - 1] != b) gstart[b] = i;
    if (i == N_NODES - 1 || batch[i + 1] != b) gend[b] = i + 1;
  }
}

__global__ void count_edges_kernel(const int* __restrict__ dst, int* __restrict__ cnt) {
  int e = blockIdx.x * 256 + threadIdx.x;
  if (e < N_EDGES) atomicAdd(&cnt[dst[e]], 1);
}

__global__ void scan_blocks_kernel(const int* __restrict__ cnt, int* __restrict__ partial,
                                   int* __restrict__ bsums, int n) {
  __shared__ int buf[256];
  int tid = threadIdx.x;
  int i = blockIdx.x * 256 + tid;
  buf[tid] = (i < n) ? cnt[i] : 0;
  __syncthreads();
  #pragma unroll
  for (int off = 1; off < 256; off <<= 1) {
    int t = (tid >= off) ? buf[tid - off] : 0;
    __syncthreads();
    buf[tid] += t;
    __syncthreads();
  }
  if (i < n) partial[i] = buf[tid];
  if (tid == 255) bsums[blockIdx.x] = buf[255];
}

__global__ void scan_sums_kernel(int* __restrict__ bsums, int nblk) {
  __shared__ int buf[256];
  int tid = threadIdx.x;
  buf[tid] = (tid < nblk) ? bsums[tid] : 0;
  __syncthreads();
  #pragma unroll
  for (int off = 1; off < 256; off <<= 1) {
    int t = (tid >= off) ? buf[tid - off] : 0;
    __syncthreads();
    buf[tid] += t;
    __syncthreads();
  }
  if (tid < nblk) bsums[tid] = buf[tid];
}

// writes rowp AND the self-loop entry + fillpos (fill_self merged: rowp[i] = rowp[i+1]-cnt[i])
__global__ void scan_write_kernel(const int* __restrict__ partial, const int* __restrict__ bsums,
                                  const int* __restrict__ cnt,
                                  int* __restrict__ rowp, int* __restrict__ col,
                                  int* __restrict__ fillpos, int n) {
  int i = blockIdx.x * 256 + threadIdx.x;
  if (i < n) {
    int b = blockIdx.x;
    int off = (b > 0) ? bsums[b - 1] : 0;
    int r1 = partial[i] + off;
    rowp[i + 1] = r1;
    if (i == 0) rowp[0] = 0;
    int p = r1 - cnt[i];   // == rowp[i]
    col[p] = i;            // self loop FIRST in each row (layer_fused relies on this)
    fillpos[i] = p + 1;
  }
}

__global__ void fill_edges_kernel(const int* __restrict__ src, const int* __restrict__ dst,
                                  int* __restrict__ fillpos, int* __restrict__ col) {
  int e = blockIdx.x * 256 + threadIdx.x;
  if (e < N_EDGES) {
    int d = dst[e];
    int p = atomicAdd(&fillpos[d], 1);
    col[p] = src[e];
  }
}

// ---------------- MFMA GEMM tiles ----------------
#define GTM 128
#define GTK 64
// LDB 76: row stride 38 dwords == 6 mod 32, gcd(6,32)=2 -> 16 distinct bank
// start positions for the 16 fragment rows (2 lanes each) -> conflict-free
// ds_read_b128. LDB=72 had 8-way pileup (2.0M conflict cycles, round-7 PMC).
#define LDB 76
#define SSTR 132

// input projection with fused fp32->fp16 cast of A and W (K = 64 = one chunk)
__global__ __launch_bounds__(256) void gemm_proj_kernel(
    const float* __restrict__ A, const float* __restrict__ W,
    const float* __restrict__ bias, u16* __restrict__ outh, int M)
{
  __shared__ u16 smem[2 * GTM * LDB];
  u16* As = smem;
  u16* Bs = smem + GTM * LDB;
  int tid = threadIdx.x;
  int lane = tid & 63;
  int wave = tid >> 6;
  int wm = (wave >> 1) * 64;
  int wn = (wave & 1) * 64;
  int bm = blockIdx.y * GTM;
  int n0 = blockIdx.x * 128;

  floatx4 zero4 = {0.f, 0.f, 0.f, 0.f};
  floatx4 acc[4][4];
  #pragma unroll
  for (int i = 0; i < 4; i++)
    #pragma unroll
    for (int j = 0; j < 4; j++) acc[i][j] = zero4;

  int q8 = (lane >> 4) * 8;
  int mrow = lane & 15;

  // stage (cast in-register): 128 rows x 64 cols, fp32 source
  {
    int r0 = tid >> 4;          // 0..15
    int c4 = (tid & 15) * 4;    // 0..60
    #pragma unroll
    for (int p = 0; p < 8; p++) {
      int row = r0 + p * 16;
      int gr = bm + row;
      float4 av = {0.f, 0.f, 0.f, 0.f};
      if (gr < M) av = *(const float4*)&A[(size_t)gr * IN_DIM + c4];
      ushort4 oa;
      oa.x = f2h(av.x); oa.y = f2h(av.y); oa.z = f2h(av.z); oa.w = f2h(av.w);
      *(ushort4*)&As[row * LDB + c4] = oa;
      float4 bv = *(const float4*)&W[(size_t)(n0 + row) * IN_DIM + c4];
      ushort4 ob;
      ob.x = f2h(bv.x); ob.y = f2h(bv.y); ob.z = f2h(bv.z); ob.w = f2h(bv.w);
      *(ushort4*)&Bs[row * LDB + c4] = ob;
    }
  }
  __syncthreads();
  #pragma unroll
  for (int h = 0; h < 2; h++) {
    half8 af[4], bf[4];
    #pragma unroll
    for (int i = 0; i < 4; i++)
      af[i] = *(const half8*)&As[(wm + i * 16 + mrow) * LDB + h * 32 + q8];
    #pragma unroll
    for (int j = 0; j < 4; j++)
      bf[j] = *(const half8*)&Bs[(wn + j * 16 + mrow) * LDB + h * 32 + q8];
    #pragma unroll
    for (int i = 0; i < 4; i++)
      #pragma unroll
      for (int j = 0; j < 4; j++)
        acc[i][j] = __builtin_amdgcn_mfma_f32_16x16x32_f16(af[i], bf[j], acc[i][j], 0, 0, 0);
  }

  __syncthreads();
  u16* stage = smem;
  int ccol = lane & 15;
  int crow4 = (lane >> 4) * 4;
  #pragma unroll
  for (int j = 0; j < 4; j++) {
    float bv = bias[n0 + wn + j * 16 + ccol];
    #pragma unroll
    for (int i = 0; i < 4; i++) {
      #pragma unroll
      for (int r = 0; r < 4; r++) {
        int row = wm + i * 16 + crow4 + r;
        stage[row * SSTR + wn + j * 16 + ccol] = f2h(acc[i][j][r] + bv);
      }
    }
  }
  __syncthreads();
  int rr = tid >> 1;
  int c0 = (tid & 1) * 64;
  int grow = bm + rr;
  if (grow < M) {
    const ushort4* sp = (const ushort4*)&stage[rr * SSTR + c0];
    ushort4* gp = (ushort4*)&outh[(size_t)grow * H + n0 + c0];
    #pragma unroll
    for (int q = 0; q < 16; q++) gp[q] = sp[q];
  }
}

// ---------------- dual GEMM v5: 64-row m-tiles, LDB=76 conflict-free ----------------
#define DTM 64
#define SSTR2 132

__global__ __launch_bounds__(256) void gemm_dual3_kernel(
    const u16* __restrict__ A, const u16* __restrict__ Wlb, const u16* __restrict__ Wrb,
    const float* __restrict__ biasL, const float* __restrict__ biasR,
    u16* __restrict__ outL, u16* __restrict__ outR, int M)
{
  __shared__ u16 As[DTM * LDB];
  __shared__ u16 Bs[128 * LDB];
  int tid = threadIdx.x;
  int lane = tid & 63;
  int wave = tid >> 6;
  int wn = wave * 32;
  int nt = blockIdx.x;
  int bm = blockIdx.y * DTM;
  const u16* W = (nt < 2) ? Wlb : Wrb;
  const float* bias = (nt < 2) ? biasL : biasR;
  u16* outp = (nt < 2) ? outL : outR;
  int n0 = (nt & 1) * 128;
  int mrow = lane & 15;
  int q8 = (lane >> 4) * 8;
  int ccol = lane & 15;
  int crow4 = (lane >> 4) * 4;
  int lr = tid >> 3;
  int lc = (tid & 7) * 8;

  floatx4 zero4 = {0.f, 0.f, 0.f, 0.f};
  floatx4 acc[4][2];
  #pragma unroll
  for (int i = 0; i < 4; i++) {
    acc[i][0] = zero4;
    acc[i][1] = zero4;
  }

  for (int k0 = 0; k0 < H; k0 += 64) {
    __syncthreads();
    #pragma unroll
    for (int p = 0; p < 2; p++) {
      int row = lr + p * 32;
      int gr = bm + row;
      uint4 av = {0, 0, 0, 0};
      if (gr < M) av = *(const uint4*)&A[(size_t)gr * H + k0 + lc];
      *(uint4*)&As[row * LDB + lc] = av;
    }
    #pragma unroll
    for (int p = 0; p < 4; p++) {
      int row = lr + p * 32;
      uint4 bv = *(const uint4*)&W[(size_t)(n0 + row) * H + k0 + lc];
      *(uint4*)&Bs[row * LDB + lc] = bv;
    }
    __syncthreads();
    #pragma unroll
    for (int h = 0; h < 2; h++) {
      half8 af[4], bf[2];
      #pragma unroll
      for (int i = 0; i < 4; i++)
        af[i] = *(const half8*)&As[(i * 16 + mrow) * LDB + h * 32 + q8];
      #pragma unroll
      for (int j = 0; j < 2; j++)
        bf[j] = *(const half8*)&Bs[(wn + j * 16 + mrow) * LDB + h * 32 + q8];
      #pragma unroll
      for (int i = 0; i < 4; i++)
        #pragma unroll
        for (int j = 0; j < 2; j++)
          acc[i][j] = __builtin_amdgcn_mfma_f32_16x16x32_f16(af[i], bf[j], acc[i][j], 0, 0, 0);
    }
  }

  __syncthreads();
  u16* stage = Bs;
  #pragma unroll
  for (int j = 0; j < 2; j++) {
    float bv = bias[n0 + wn + j * 16 + ccol];
    #pragma unroll
    for (int i = 0; i < 4; i++) {
      #pragma unroll
      for (int r = 0; r < 4; r++) {
        int row = i * 16 + crow4 + r;
        stage[row * SSTR2 + wn + j * 16 + ccol] = f2h(acc[i][j][r] + bv);
      }
    }
  }
  __syncthreads();
  #pragma unroll
  for (int pass = 0; pass < 4; pass++) {
    int row = pass * 16 + (tid >> 4);
    int cu = (tid & 15) * 8;
    int grow = bm + row;
    if (grow < M) {
      *(uint4*)&outp[(size_t)grow * H + n0 + cu] =
          *(const uint4*)&stage[row * SSTR2 + cu];
    }
  }
}

// ---------------- gate GEMM v2: dual3-style 64-row m-tiles, 128-col n-tile per block ----------------
__global__ __launch_bounds__(256) void gemm_gate2_kernel(
    const u16* __restrict__ A, const u16* __restrict__ W,
    const float* __restrict__ bias, const float* __restrict__ Wg2,
    float* __restrict__ gate, int M)
{
  __shared__ u16 As[DTM * LDB];
  __shared__ u16 Bs[128 * LDB];
  int tid = threadIdx.x;
  int lane = tid & 63;
  int wave = tid >> 6;
  int wn = wave * 32;
  int n0 = blockIdx.x * 128;
  int bm = blockIdx.y * DTM;
  int mrow = lane & 15;
  int q8 = (lane >> 4) * 8;
  int ccol = lane & 15;
  int crow4 = (lane >> 4) * 4;
  int lr = tid >> 3;
  int lc = (tid & 7) * 8;

  floatx4 zero4 = {0.f, 0.f, 0.f, 0.f};
  floatx4 acc[4][2];
  #pragma unroll
  for (int i = 0; i < 4; i++) {
    acc[i][0] = zero4;
    acc[i][1] = zero4;
  }

  for (int k0 = 0; k0 < H; k0 += 64) {
    __syncthreads();
    #pragma unroll
    for (int p = 0; p < 2; p++) {
      int row = lr + p * 32;
      int gr = bm + row;
      uint4 av = {0, 0, 0, 0};
      if (gr < M) av = *(const uint4*)&A[(size_t)gr * H + k0 + lc];
      *(uint4*)&As[row * LDB + lc] = av;
    }
    #pragma unroll
    for (int p = 0; p < 4; p++) {
      int row = lr + p * 32;
      uint4 bv = *(const uint4*)&W[(size_t)(n0 + row) * H + k0 + lc];
      *(uint4*)&Bs[row * LDB + lc] = bv;
    }
    __syncthreads();
    #pragma unroll
    for (int h = 0; h < 2; h++) {
      half8 af[4], bf[2];
      #pragma unroll
      for (int i = 0; i < 4; i++)
        af[i] = *(const half8*)&As[(i * 16 + mrow) * LDB + h * 32 + q8];
      #pragma unroll
      for (int j = 0; j < 2; j++)
        bf[j] = *(const half8*)&Bs[(wn + j * 16 + mrow) * LDB + h * 32 + q8];
      #pragma unroll
      for (int i = 0; i < 4; i++)
        #pragma unroll
        for (int j = 0; j < 2; j++)
          acc[i][j] = __builtin_amdgcn_mfma_f32_16x16x32_f16(af[i], bf[j], acc[i][j], 0, 0, 0);
    }
  }

  float bv[2], wv[2];
  #pragma unroll
  for (int j = 0; j < 2; j++) {
    int c = n0 + wn + j * 16 + ccol;
    bv[j] = bias[c];
    wv[j] = Wg2[c];
  }
  #pragma unroll
  for (int i = 0; i < 4; i++) {
    #pragma unroll
    for (int r = 0; r < 4; r++) {
      float p = fmaxf(acc[i][0][r] + bv[0], 0.f) * wv[0]
              + fmaxf(acc[i][1][r] + bv[1], 0.f) * wv[1];
      p += __shfl_xor(p, 1, 64);
      p += __shfl_xor(p, 2, 64);
      p += __shfl_xor(p, 4, 64);
      p += __shfl_xor(p, 8, 64);
      int row = bm + i * 16 + crow4 + r;
      if ((lane & 15) == 0 && row < M) atomicAdd(&gate[row], p);
    }
  }
}

// ---------------- fused edge softmax + aggregate + LN + residual ----------------
// v7: v6 (lane-partitioned dual-node waves) + 4-wide edge loop per half.
// Round-8 counters: VALUBusy 53%, HBM 41%, occupancy 57% -> latency-bound on
// the SERIAL per-node iteration chain (mean degree 6 = 3 sequential 2-edge
// iterations, each gated by gather latency). 4-wide cuts that to 2 iterations
// with 4 gathers in flight per half; shuffle/edge unchanged (2.5); padding
// slots clamp to the self row (L1-hot, weight 0 -> no extra HBM, math exact).
// Unlike round-5's failed conditional prefetch, this is in-iteration WIDTH
// (the v4 pattern that worked) — the compiler keeps scheduling control.
__global__ __launch_bounds__(256) void layer_fused_kernel(
    const u16* __restrict__ xl, const u16* __restrict__ xr,
    u16* __restrict__ xst,
    const int* __restrict__ rowp, const int* __restrict__ col,
    const float* __restrict__ att, const float* __restrict__ bias_c,
    const float* __restrict__ ln_g, const float* __restrict__ ln_b)
{
  int lane = threadIdx.x & 63;
  int wid = blockIdx.x * 4 + (threadIdx.x >> 6);   // wave id, < N_NODES/2
  int half = lane >> 5;
  int v = wid * 2 + half;                          // node per half (always < N_NODES)
  int f8 = (lane & 31) << 3;                       // 8 features per lane

  float4 attA = *(const float4*)&att[f8];
  float4 attB = *(const float4*)&att[f8 + 4];
  h2 att0, att1, att2, att3;
  att0[0] = (_Float16)attA.x; att0[1] = (_Float16)attA.y;
  att1[0] = (_Float16)attA.z; att1[1] = (_Float16)attA.w;
  att2[0] = (_Float16)attB.x; att2[1] = (_Float16)attB.y;
  att3[0] = (_Float16)attB.z; att3[1] = (_Float16)attB.w;
  h2 nsl; nsl[0] = (_Float16)NEG_SLOPE; nsl[1] = (_Float16)NEG_SLOPE;

  size_t rowbase = (size_t)v * H + f8;
  int beg = rowp[v], end = rowp[v + 1];
  uint4 xru = *(const uint4*)&xr[rowbase];
  uint4 su  = *(const uint4*)&xl[rowbase];
  uint4 xres = *(const uint4*)&xst[rowbase];

  h2 xr0 = u2h2(xru.x), xr1 = u2h2(xru.y), xr2 = u2h2(xru.z), xr3 = u2h2(xru.w);
  h2 s0 = u2h2(su.x), s1 = u2h2(su.y), s2 = u2h2(su.z), s3 = u2h2(su.w);

  // self edge (first in row): anchor m, weight exp(0)=1 (5-stage half reduce)
  float m;
  {
    h2 t; float pe = 0.f;
    t = s0 + xr0; t = __builtin_elementwise_max(t, t * nsl); pe = fdot2f(t, att0, pe);
    t = s1 + xr1; t = __builtin_elementwise_max(t, t * nsl); pe = fdot2f(t, att1, pe);
    t = s2 + xr2; t = __builtin_elementwise_max(t, t * nsl); pe = fdot2f(t, att2, pe);
    t = s3 + xr3; t = __builtin_elementwise_max(t, t * nsl); pe = fdot2f(t, att3, pe);
    m = half_reduce_sum(pe);
  }
  float d = 1.0f;
  float o0 = (float)s0[0], o1 = (float)s0[1];
  float o2 = (float)s1[0], o3 = (float)s1[1];
  float o4 = (float)s2[0], o5 = (float)s2[1];
  float o6 = (float)s3[0], o7 = (float)s3[1];

  // edge loop: 4 edges per half per iteration; trip count = max over both halves
  int p = beg + 1;
  int rem = end - p;                         // real edges for this half's node
  int it_half = (rem + 3) >> 2;              // ceil(rem/4)
  int it_other = __shfl_xor(it_half, 32, 64);
  int iters = it_half > it_other ? it_half : it_other;

  for (int i = 0; i < iters; i++) {
    bool e0 = p < end;
    bool e1 = p + 1 < end;
    bool e2 = p + 2 < end;
    bool e3 = p + 3 < end;
    int ua = col[e0 ? p : beg];              // clamp to self row (L1-hot, w=0)
    int ub = col[e1 ? p + 1 : beg];
    int uc = col[e2 ? p + 2 : beg];
    int ud = col[e3 ? p + 3 : beg];
    uint4 A = *(const uint4*)&xl[(size_t)ua * H + f8];
    uint4 B = *(const uint4*)&xl[(size_t)ub * H + f8];
    uint4 C = *(const uint4*)&xl[(size_t)uc * H + f8];
    uint4 D = *(const uint4*)&xl[(size_t)ud * H + f8];
    h2 a0 = u2h2(A.x), a1 = u2h2(A.y), a2 = u2h2(A.z), a3 = u2h2(A.w);
    h2 b0 = u2h2(B.x), b1 = u2h2(B.y), b2 = u2h2(B.z), b3 = u2h2(B.w);
    h2 c0_ = u2h2(C.x), c1_ = u2h2(C.y), c2_ = u2h2(C.z), c3_ = u2h2(C.w);
    h2 d0_ = u2h2(D.x), d1_ = u2h2(D.y), d2_ = u2h2(D.z), d3_ = u2h2(D.w);
    float pa = 0.f, pb = 0.f, pc = 0.f, pd = 0.f;
    {
      h2 t;
      t = a0 + xr0; t = __builtin_elementwise_max(t, t * nsl); pa = fdot2f(t, att0, pa);
      t = b0 + xr0; t = __builtin_elementwise_max(t, t * nsl); pb = fdot2f(t, att0, pb);
      t = c0_ + xr0; t = __builtin_elementwise_max(t, t * nsl); pc = fdot2f(t, att0, pc);
      t = d0_ + xr0; t = __builtin_elementwise_max(t, t * nsl); pd = fdot2f(t, att0, pd);
      t = a1 + xr1; t = __builtin_elementwise_max(t, t * nsl); pa = fdot2f(t, att1, pa);
      t = b1 + xr1; t = __builtin_elementwise_max(t, t * nsl); pb = fdot2f(t, att1, pb);
      t = c1_ + xr1; t = __builtin_elementwise_max(t, t * nsl); pc = fdot2f(t, att1, pc);
      t = d1_ + xr1; t = __builtin_elementwise_max(t, t * nsl); pd = fdot2f(t, att1, pd);
      t = a2 + xr2; t = __builtin_elementwise_max(t, t * nsl); pa = fdot2f(t, att2, pa);
      t = b2 + xr2; t = __builtin_elementwise_max(t, t * nsl); pb = fdot2f(t, att2, pb);
      t = c2_ + xr2; t = __builtin_elementwise_max(t, t * nsl); pc = fdot2f(t, att2, pc);
      t = d2_ + xr2; t = __builtin_elementwise_max(t, t * nsl); pd = fdot2f(t, att2, pd);
      t = a3 + xr3; t = __builtin_elementwise_max(t, t * nsl); pa = fdot2f(t, att3, pa);
      t = b3 + xr3; t = __builtin_elementwise_max(t, t * nsl); pb = fdot2f(t, att3, pb);
      t = c3_ + xr3; t = __builtin_elementwise_max(t, t * nsl); pc = fdot2f(t, att3, pc);
      t = d3_ + xr3; t = __builtin_elementwise_max(t, t * nsl); pd = fdot2f(t, att3, pd);
    }
    #pragma unroll
    for (int off = 1; off <= 16; off <<= 1) {
      pa += __shfl_xor(pa, off, 64);
      pb += __shfl_xor(pb, off, 64);
      pc += __shfl_xor(pc, off, 64);
      pd += __shfl_xor(pd, off, 64);
    }
    float wa = e0 ? __expf(pa - m) : 0.f;
    float wb = e1 ? __expf(pb - m) : 0.f;
    float wc = e2 ? __expf(pc - m) : 0.f;
    float wd = e3 ? __expf(pd - m) : 0.f;
    d += (wa + wb) + (wc + wd);
    o0 = fmaf(wa, (float)a0[0], fmaf(wb, (float)b0[0], fmaf(wc, (float)c0_[0], fmaf(wd, (float)d0_[0], o0))));
    o1 = fmaf(wa, (float)a0[1], fmaf(wb, (float)b0[1], fmaf(wc, (float)c0_[1], fmaf(wd, (float)d0_[1], o1))));
    o2 = fmaf(wa, (float)a1[0], fmaf(wb, (float)b1[0], fmaf(wc, (float)c1_[0], fmaf(wd, (float)d1_[0], o2))));
    o3 = fmaf(wa, (float)a1[1], fmaf(wb, (float)b1[1], fmaf(wc, (float)c1_[1], fmaf(wd, (float)d1_[1], o3))));
    o4 = fmaf(wa, (float)a2[0], fmaf(wb, (float)b2[0], fmaf(wc, (float)c2_[0], fmaf(wd, (float)d2_[0], o4))));
    o5 = fmaf(wa, (float)a2[1], fmaf(wb, (float)b2[1], fmaf(wc, (float)c2_[1], fmaf(wd, (float)d2_[1], o5))));
    o6 = fmaf(wa, (float)a3[0], fmaf(wb, (float)b3[0], fmaf(wc, (float)c3_[0], fmaf(wd, (float)d3_[0], o6))));
    o7 = fmaf(wa, (float)a3[1], fmaf(wb, (float)b3[1], fmaf(wc, (float)c3_[1], fmaf(wd, (float)d3_[1], o7))));
    p += 4;
  }

  float invd = 1.0f / d;
  float4 bcA = *(const float4*)&bias_c[f8];
  float4 bcB = *(const float4*)&bias_c[f8 + 4];
  o0 = o0 * invd + bcA.x; o1 = o1 * invd + bcA.y;
  o2 = o2 * invd + bcA.z; o3 = o3 * invd + bcA.w;
  o4 = o4 * invd + bcB.x; o5 = o5 * invd + bcB.y;
  o6 = o6 * invd + bcB.z; o7 = o7 * invd + bcB.w;

  // LN per half (each feature counted once -> exact 1/H)
  float s = ((o0 + o1) + (o2 + o3)) + ((o4 + o5) + (o6 + o7));
  s = half_reduce_sum(s);
  float mean = s * (1.0f / H);
  float c0 = o0 - mean, c1 = o1 - mean, c2 = o2 - mean, c3 = o3 - mean;
  float c4 = o4 - mean, c5 = o5 - mean, c6 = o6 - mean, c7 = o7 - mean;
  float sq = ((c0 * c0 + c1 * c1) + (c2 * c2 + c3 * c3))
           + ((c4 * c4 + c5 * c5) + (c6 * c6 + c7 * c7));
  sq = half_reduce_sum(sq);
  float rstd = rsqrtf(sq * (1.0f / H) + LN_EPS);

  float4 gA = *(const float4*)&ln_g[f8];
  float4 gB = *(const float4*)&ln_g[f8 + 4];
  float4 bA = *(const float4*)&ln_b[f8];
  float4 bB = *(const float4*)&ln_b[f8 + 4];
  h2 r0 = u2h2(xres.x), r1 = u2h2(xres.y), r2 = u2h2(xres.z), r3 = u2h2(xres.w);
  float y0 = fmaxf(fmaf(c0 * rstd, gA.x, bA.x), 0.f) + (float)r0[0];
  float y1 = fmaxf(fmaf(c1 * rstd, gA.y, bA.y), 0.f) + (float)r0[1];
  float y2 = fmaxf(fmaf(c2 * rstd, gA.z, bA.z), 0.f) + (float)r1[0];
  float y3 = fmaxf(fmaf(c3 * rstd, gA.w, bA.w), 0.f) + (float)r1[1];
  float y4 = fmaxf(fmaf(c4 * rstd, gB.x, bB.x), 0.f) + (float)r2[0];
  float y5 = fmaxf(fmaf(c5 * rstd, gB.y, bB.y), 0.f) + (float)r2[1];
  float y6 = fmaxf(fmaf(c6 * rstd, gB.z, bB.z), 0.f) + (float)r3[0];
  float y7 = fmaxf(fmaf(c7 * rstd, gB.w, bB.w), 0.f) + (float)r3[1];
  uint4 outv;
  outv.x = (unsigned)f2h(y0) | ((unsigned)f2h(y1) << 16);
  outv.y = (unsigned)f2h(y2) | ((unsigned)f2h(y3) << 16);
  outv.z = (unsigned)f2h(y4) | ((unsigned)f2h(y5) << 16);
  outv.w = (unsigned)f2h(y6) | ((unsigned)f2h(y7) << 16);
  *(uint4*)&xst[rowbase] = outv;
}

// ---------------- pooling: per-graph softmax stats (+ pooled zero) ----------------
__global__ __launch_bounds__(256) void pool_prep_kernel(
    const float* __restrict__ gate, const int* __restrict__ gstart,
    const int* __restrict__ gend, float* __restrict__ gmax, float* __restrict__ gdinv,
    float* __restrict__ pooled)
{
  __shared__ float red[256];
  int g = blockIdx.x, tid = threadIdx.x;
  pooled[(size_t)g * H + tid] = 0.f;
  int s = gstart[g], e = gend[g];
  float lm = -INFINITY;
  for (int i = s + tid; i < e; i += 256) lm = fmaxf(lm, gate[i]);
  red[tid] = lm;
  __syncthreads();
  for (int off = 128; off; off >>= 1) {
    if (tid < off) red[tid] = fmaxf(red[tid], red[tid + off]);
    __syncthreads();
  }
  float m = red[0];
  __syncthreads();
  float lsum = 0.0f;
  for (int i = s + tid; i < e; i += 256) lsum += __expf(gate[i] - m);
  red[tid] = lsum;
  __syncthreads();
  for (int off = 128; off; off >>= 1) {
    if (tid < off) red[tid] += red[tid + off];
    __syncthreads();
  }
  if (tid == 0) {
    gmax[g] = m;
    gdinv[g] = (s < e) ? 1.0f / red[0] : 0.0f;
  }
}

// ---------------- pooling: weighted accumulate (64 nodes per block, fp16 x) ----------------
__global__ __launch_bounds__(256) void pool_accum_kernel(
    const float* __restrict__ gate, const u16* __restrict__ xh,
    const int* __restrict__ batch, const float* __restrict__ gmax,
    const float* __restrict__ gdinv, float* __restrict__ pooled)
{
  __shared__ float wl[64];
  __shared__ int gl[64];
  int b0 = blockIdx.x * 64;
  int tid = threadIdx.x;
  if (tid < 64) {
    int v = b0 + tid;
    if (v < N_NODES) {
      int g = batch[v];
      gl[tid] = g;
      wl[tid] = __expf(gate[v] - gmax[g]) * gdinv[g];
    } else {
      gl[tid] = -1;
      wl[tid] = 0.f;
    }
  }
  __syncthreads();
  int cnt = min(64, N_NODES - b0);
  float acc = 0.f;
  int cur = gl[0];
  for (int j = 0; j < cnt; j++) {
    int g = gl[j];
    if (g != cur) {
      atomicAdd(&pooled[(size_t)cur * H + tid], acc);
      acc = 0.f;
      cur = g;
    }
    acc += wl[j] * h2f(xh[(size_t)(b0 + j) * H + tid]);
  }
  if (cur >= 0) atomicAdd(&pooled[(size_t)cur * H + tid], acc);
}

// ---------------- fused head: pooled -> z -> {cls, r1} -> residual ----------------
__global__ __launch_bounds__(256) void head_kernel(
    const float* __restrict__ pooled,
    const float* __restrict__ Ws, const float* __restrict__ bs,
    const float* __restrict__ Wc, const float* __restrict__ bc,
    const float* __restrict__ Wr1, const float* __restrict__ br1,
    const float* __restrict__ Wr2, const float* __restrict__ br2,
    float* __restrict__ out)
{
  __shared__ float psh[256];
  __shared__ float zsh[256];
  __shared__ float r1sh[128];
  int g = blockIdx.x, tid = threadIdx.x;
  psh[tid] = pooled[(size_t)g * H + tid];
  __syncthreads();
  {
    float acc = bs[tid];
    const float4* wr = (const float4*)&Ws[(size_t)tid * H];
    for (int k4 = 0; k4 < H / 4; k4++) {
      float4 wv = wr[k4];
      float4 av = *(const float4*)&psh[k4 * 4];
      acc += av.x * wv.x + av.y * wv.y + av.z * wv.z + av.w * wv.w;
    }
    zsh[tid] = fmaxf(acc, 0.f);
  }
  __syncthreads();
  if (tid < NB) {
    float acc = bc[tid];
    const float4* wr = (const float4*)&Wc[(size_t)tid * H];
    for (int k4 = 0; k4 < H / 4; k4++) {
      float4 wv = wr[k4];
      float4 av = *(const float4*)&zsh[k4 * 4];
      acc += av.x * wv.x + av.y * wv.y + av.z * wv.z + av.w * wv.w;
    }
    out[(size_t)g * NB + tid] = acc;
  }
  if (tid < 128) {
    float acc = br1[tid];
    const float4* wr = (const float4*)&Wr1[(size_t)tid * H];
    for (int k4 = 0; k4 < H / 4; k4++) {
      float4 wv = wr[k4];
      float4 av = *(const float4*)&zsh[k4 * 4];
      acc += av.x * wv.x + av.y * wv.y + av.z * wv.z + av.w * wv.w;
    }
    r1sh[tid] = fmaxf(acc, 0.f);
  }
  __syncthreads();
  if (tid < 64) {
    float s2 = r1sh[tid] * Wr2[tid] + r1sh[tid + 64] * Wr2[tid + 64];
    s2 = wave_reduce_sum(s2);
    if (tid == 0) out[(size_t)NGRAPH * NB + g] = tanhf(s2 + br2[0]);
  }
}

// ---------------- launcher ----------------
extern "C" void kernel_launch(void* const* d_in, const int* in_sizes, int n_in,
                              void* d_out, int out_size, void* d_ws, size_t ws_size,
                              hipStream_t stream) {
  const float* x_in   = (const float*)d_in[0];
  const int*   eidx   = (const int*)d_in[1];
  const int*   batch  = (const int*)d_in[2];
  const float* W_in   = (const float*)d_in[3];
  const float* b_in   = (const float*)d_in[4];
  const float* Wl     = (const float*)d_in[5];
  const float* bl     = (const float*)d_in[6];
  const float* Wr     = (const float*)d_in[7];
  const float* br     = (const float*)d_in[8];
  const float* att    = (const float*)d_in[9];
  const float* bias_c = (const float*)d_in[10];
  const float* ln_g   = (const float*)d_in[11];
  const float* ln_b   = (const float*)d_in[12];
  const float* Wg1    = (const float*)d_in[13];
  const float* bg1    = (const float*)d_in[14];
  const float* Wg2    = (const float*)d_in[15];
  const float* bg2    = (const float*)d_in[16];
  const float* Ws     = (const float*)d_in[17];
  const float* bs     = (const float*)d_in[18];
  const float* Wc     = (const float*)d_in[19];
  const float* bc     = (const float*)d_in[20];
  const float* Wr1    = (const float*)d_in[21];
  const float* br1    = (const float*)d_in[22];
  const float* Wr2    = (const float*)d_in[23];
  const float* br2    = (const float*)d_in[24];
  float* out = (float*)d_out;

  char* w = (char*)d_ws;
  u16* x_h    = (u16*)w;    w += sizeof(u16) * (size_t)N_NODES * H;
  u16* xl_h   = (u16*)w;    w += sizeof(u16) * (size_t)N_NODES * H;
  u16* xr_h   = (u16*)w;    w += sizeof(u16) * (size_t)N_NODES * H;
  u16* wl_h   = (u16*)w;    w += sizeof(u16) * (size_t)LAYERS * H * H;
  u16* wr_h   = (u16*)w;    w += sizeof(u16) * (size_t)LAYERS * H * H;
  u16* wg1_h  = (u16*)w;    w += sizeof(u16) * (size_t)H * H;
  float* pooled = (float*)w; w += sizeof(float) * NGRAPH * H;
  float* gate = (float*)w;  w += sizeof(float) * N_NODES;
  float* gmax = (float*)w;  w += sizeof(float) * NGRAPH;
  float* gdinv= (float*)w;  w += sizeof(float) * NGRAPH;
  int* cnt    = (int*)w;    w += sizeof(int) * N_NODES;
  int* rowp   = (int*)w;    w += sizeof(int) * (N_NODES + 1);
  int* col    = (int*)w;    w += sizeof(int) * EE;
  int* partial= (int*)w;    w += sizeof(int) * N_NODES;
  int* bsums  = (int*)w;    w += sizeof(int) * 256;
  int* gstart = (int*)w;    w += sizeof(int) * NGRAPH;
  int* gend   = (int*)w;    w += sizeof(int) * NGRAPH;
  (void)ws_size; (void)n_in; (void)in_sizes; (void)out_size;

  const int* src = eidx;
  const int* dst = eidx + N_EDGES;
  int nblkN = (N_NODES + 255) / 256;
  int nblkE = (N_EDGES + 255) / 256;
  int mtiles = (N_NODES + GTM - 1) / GTM;
  int mtiles2 = (N_NODES + DTM - 1) / DTM;

  // CSR build + gate/bounds init (merged), self-loop entry written during scan_write
  init_kernel<<<nblkN, 256, 0, stream>>>(cnt, gate, bg2, batch, gstart, gend);
  count_edges_kernel<<<nblkE, 256, 0, stream>>>(dst, cnt);
  scan_blocks_kernel<<<nblkN, 256, 0, stream>>>(cnt, partial, bsums, N_NODES);
  scan_sums_kernel<<<1, 256, 0, stream>>>(bsums, nblkN);
  scan_write_kernel<<<nblkN, 256, 0, stream>>>(partial, bsums, cnt, rowp, col, cnt, N_NODES);
  fill_edges_kernel<<<nblkE, 256, 0, stream>>>(src, dst, cnt, col);

  // weight casts (x_in cast fused into proj)
  {
    int maxn4 = LAYERS * H * H / 4;
    dim3 gcast((maxn4 + 255) / 256, 3);
    cast_weights_kernel<<<gcast, 256, 0, stream>>>(Wg1, Wl, Wr, wg1_h, wl_h, wr_h);
  }

  // input projection (fp32 inputs, fused cast) -> x_h
  dim3 gproj(2, mtiles);
  gemm_proj_kernel<<<gproj, 256, 0, stream>>>(x_in, W_in, b_in, x_h, N_NODES);

  // v6/v7 layer_fused: one wave serves 2 nodes -> 25000 waves, 6250 blocks
  int nblkV = (N_NODES / 2 + 3) / 4;
  dim3 gdual(4, mtiles2);
  for (int l = 0; l < LAYERS; l++) {
    gemm_dual3_kernel<<<gdual, 256, 0, stream>>>(x_h,
        wl_h + (size_t)l * H * H, wr_h + (size_t)l * H * H,
        bl + l * H, br + l * H, xl_h, xr_h, N_NODES);
    layer_fused_kernel<<<nblkV, 256, 0, stream>>>(xl_h, xr_h, x_h, rowp, col,
        att + l * H, bias_c + l * H, ln_g + l * H, ln_b + l * H);
  }

  // gate (fused GEMM + row-dot); gate pre-initialized by init_kernel
  dim3 ggate(2, mtiles2);
  gemm_gate2_kernel<<<ggate, 256, 0, stream>>>(x_h, wg1_h, bg1, Wg2, gate, N_NODES);

  // pooling
  pool_prep_kernel<<<NGRAPH, 256, 0, stream>>>(gate, gstart, gend, gmax, gdinv, pooled);
  pool_accum_kernel<<<(N_NODES + 63) / 64, 256, 0, stream>>>(gate, x_h, batch, gmax, gdinv, pooled);

  // fused heads
  head_kernel<<<NGRAPH, 256, 0, stream>>>(pooled, Ws, bs, Wc, bc, Wr1, br1, Wr2, br2, out);
}

// Round 10
// 535.772 us; speedup vs baseline: 1.0243x; 1.0243x over previous
//
#include <hip/hip_runtime.h>
#include <math.h>

#define N_NODES 50000
#define N_EDGES 300000
#define IN_DIM 64
#define H 256
#define LAYERS 4
#define NB 181
#define NGRAPH 64
#define EE (N_EDGES + N_NODES)
#define NEG_SLOPE 0.2f
#define LN_EPS 1e-5f

typedef unsigned short u16;
typedef __attribute__((ext_vector_type(8))) _Float16 half8;
typedef __attribute__((ext_vector_type(4))) float floatx4;
typedef __attribute__((ext_vector_type(2))) _Float16 h2;

__device__ __forceinline__ u16 f2h(float f) {
  _Float16 h = (_Float16)f;
  return __builtin_bit_cast(u16, h);
}
__device__ __forceinline__ float h2f(u16 b) {
  return (float)__builtin_bit_cast(_Float16, b);
}
__device__ __forceinline__ h2 u2h2(unsigned int u) {
  return __builtin_bit_cast(h2, u);
}
__device__ __forceinline__ float fdot2f(h2 a, h2 b, float c) {
  typedef __attribute__((ext_vector_type(2))) __fp16 hb;
  return __builtin_amdgcn_fdot2(__builtin_bit_cast(hb, a),
                                __builtin_bit_cast(hb, b), c, false);
}

__device__ __forceinline__ float wave_reduce_sum(float v) {
  #pragma unroll
  for (int off = 32; off > 0; off >>= 1) v += __shfl_xor(v, off, 64);
  return v;
}

// 5-stage reduce within a 32-lane half (offsets <32 never cross halves)
__device__ __forceinline__ float half_reduce_sum(float v) {
  v += __shfl_xor(v, 1, 64);
  v += __shfl_xor(v, 2, 64);
  v += __shfl_xor(v, 4, 64);
  v += __shfl_xor(v, 8, 64);
  v += __shfl_xor(v, 16, 64);
  return v;
}

// ---------------- weight casts (Wg1, Wl, Wr) ----------------
__global__ void cast_weights_kernel(
    const float* __restrict__ Wg1,
    const float* __restrict__ Wl, const float* __restrict__ Wr,
    u16* __restrict__ wg1_h, u16* __restrict__ wl_h, u16* __restrict__ wr_h)
{
  int i = blockIdx.x * 256 + threadIdx.x;
  int which = blockIdx.y;
  const float* s; u16* dd; int n4;
  if (which == 0)      { s = Wg1;  dd = wg1_h; n4 = H * H / 4; }
  else if (which == 1) { s = Wl;   dd = wl_h;  n4 = LAYERS * H * H / 4; }
  else                 { s = Wr;   dd = wr_h;  n4 = LAYERS * H * H / 4; }
  if (i < n4) {
    float4 f = ((const float4*)s)[i];
    ushort4 o;
    o.x = f2h(f.x); o.y = f2h(f.y); o.z = f2h(f.z); o.w = f2h(f.w);
    ((ushort4*)dd)[i] = o;
  }
}

// ---------------- CSR build + gate/graph-bounds init (merged) ----------------
__global__ void init_kernel(int* __restrict__ cnt,
                            float* __restrict__ gate, const float* __restrict__ bg2,
                            const int* __restrict__ batch,
                            int* __restrict__ gstart, int* __restrict__ gend) {
  int i = blockIdx.x * 256 + threadIdx.x;
  if (i < N_NODES) {
    cnt[i] = 1;  // self loop
    gate[i] = bg2[0];
    int b = batch[i];
    if (i == 0 || batch[i - 1] != b) gstart[b] = i;
    if (i == N_NODES - 1 || batch[i + 1] != b) gend[b] = i + 1;
  }
}

__global__ void count_edges_kernel(const int* __restrict__ dst, int* __restrict__ cnt) {
  int e = blockIdx.x * 256 + threadIdx.x;
  if (e < N_EDGES) atomicAdd(&cnt[dst[e]], 1);
}

__global__ void scan_blocks_kernel(const int* __restrict__ cnt, int* __restrict__ partial,
                                   int* __restrict__ bsums, int n) {
  __shared__ int buf[256];
  int tid = threadIdx.x;
  int i = blockIdx.x * 256 + tid;
  buf[tid] = (i < n) ? cnt[i] : 0;
  __syncthreads();
  #pragma unroll
  for (int off = 1; off < 256; off <<= 1) {
    int t = (tid >= off) ? buf[tid - off] : 0;
    __syncthreads();
    buf[tid] += t;
    __syncthreads();
  }
  if (i < n) partial[i] = buf[tid];
  if (tid == 255) bsums[blockIdx.x] = buf[255];
}

__global__ void scan_sums_kernel(int* __restrict__ bsums, int nblk) {
  __shared__ int buf[256];
  int tid = threadIdx.x;
  buf[tid] = (tid < nblk) ? bsums[tid] : 0;
  __syncthreads();
  #pragma unroll
  for (int off = 1; off < 256; off <<= 1) {
    int t = (tid >= off) ? buf[tid - off] : 0;
    __syncthreads();
    buf[tid] += t;
    __syncthreads();
  }
  if (tid < nblk) bsums[tid] = buf[tid];
}

// writes rowp AND the self-loop entry + fillpos (fill_self merged: rowp[i] = rowp[i+1]-cnt[i])
__global__ void scan_write_kernel(const int* __restrict__ partial, const int* __restrict__ bsums,
                                  const int* __restrict__ cnt,
                                  int* __restrict__ rowp, int* __restrict__ col,
                                  int* __restrict__ fillpos, int n) {
  int i = blockIdx.x * 256 + threadIdx.x;
  if (i < n) {
    int b = blockIdx.x;
    int off = (b > 0) ? bsums[b - 1] : 0;
    int r1 = partial[i] + off;
    rowp[i + 1] = r1;
    if (i == 0) rowp[0] = 0;
    int p = r1 - cnt[i];   // == rowp[i]
    col[p] = i;            // self loop FIRST in each row (layer_fused relies on this)
    fillpos[i] = p + 1;
  }
}

__global__ void fill_edges_kernel(const int* __restrict__ src, const int* __restrict__ dst,
                                  int* __restrict__ fillpos, int* __restrict__ col) {
  int e = blockIdx.x * 256 + threadIdx.x;
  if (e < N_EDGES) {
    int d = dst[e];
    int p = atomicAdd(&fillpos[d], 1);
    col[p] = src[e];
  }
}

// ---------------- MFMA GEMM tiles ----------------
#define GTM 128
#define GTK 64
// LDB 76: row stride 38 dwords == 6 mod 32, gcd(6,32)=2 -> 16 distinct bank
// start positions for the 16 fragment rows (2 lanes each) -> conflict-free
// ds_read_b128. LDB=72 had 8-way pileup (2.0M conflict cycles, round-7 PMC).
#define LDB 76
#define SSTR 132

// input projection with fused fp32->fp16 cast of A and W (K = 64 = one chunk)
__global__ __launch_bounds__(256) void gemm_proj_kernel(
    const float* __restrict__ A, const float* __restrict__ W,
    const float* __restrict__ bias, u16* __restrict__ outh, int M)
{
  __shared__ u16 smem[2 * GTM * LDB];
  u16* As = smem;
  u16* Bs = smem + GTM * LDB;
  int tid = threadIdx.x;
  int lane = tid & 63;
  int wave = tid >> 6;
  int wm = (wave >> 1) * 64;
  int wn = (wave & 1) * 64;
  int bm = blockIdx.y * GTM;
  int n0 = blockIdx.x * 128;

  floatx4 zero4 = {0.f, 0.f, 0.f, 0.f};
  floatx4 acc[4][4];
  #pragma unroll
  for (int i = 0; i < 4; i++)
    #pragma unroll
    for (int j = 0; j < 4; j++) acc[i][j] = zero4;

  int q8 = (lane >> 4) * 8;
  int mrow = lane & 15;

  // stage (cast in-register): 128 rows x 64 cols, fp32 source
  {
    int r0 = tid >> 4;          // 0..15
    int c4 = (tid & 15) * 4;    // 0..60
    #pragma unroll
    for (int p = 0; p < 8; p++) {
      int row = r0 + p * 16;
      int gr = bm + row;
      float4 av = {0.f, 0.f, 0.f, 0.f};
      if (gr < M) av = *(const float4*)&A[(size_t)gr * IN_DIM + c4];
      ushort4 oa;
      oa.x = f2h(av.x); oa.y = f2h(av.y); oa.z = f2h(av.z); oa.w = f2h(av.w);
      *(ushort4*)&As[row * LDB + c4] = oa;
      float4 bv = *(const float4*)&W[(size_t)(n0 + row) * IN_DIM + c4];
      ushort4 ob;
      ob.x = f2h(bv.x); ob.y = f2h(bv.y); ob.z = f2h(bv.z); ob.w = f2h(bv.w);
      *(ushort4*)&Bs[row * LDB + c4] = ob;
    }
  }
  __syncthreads();
  #pragma unroll
  for (int h = 0; h < 2; h++) {
    half8 af[4], bf[4];
    #pragma unroll
    for (int i = 0; i < 4; i++)
      af[i] = *(const half8*)&As[(wm + i * 16 + mrow) * LDB + h * 32 + q8];
    #pragma unroll
    for (int j = 0; j < 4; j++)
      bf[j] = *(const half8*)&Bs[(wn + j * 16 + mrow) * LDB + h * 32 + q8];
    #pragma unroll
    for (int i = 0; i < 4; i++)
      #pragma unroll
      for (int j = 0; j < 4; j++)
        acc[i][j] = __builtin_amdgcn_mfma_f32_16x16x32_f16(af[i], bf[j], acc[i][j], 0, 0, 0);
  }

  __syncthreads();
  u16* stage = smem;
  int ccol = lane & 15;
  int crow4 = (lane >> 4) * 4;
  #pragma unroll
  for (int j = 0; j < 4; j++) {
    float bv = bias[n0 + wn + j * 16 + ccol];
    #pragma unroll
    for (int i = 0; i < 4; i++) {
      #pragma unroll
      for (int r = 0; r < 4; r++) {
        int row = wm + i * 16 + crow4 + r;
        stage[row * SSTR + wn + j * 16 + ccol] = f2h(acc[i][j][r] + bv);
      }
    }
  }
  __syncthreads();
  int rr = tid >> 1;
  int c0 = (tid & 1) * 64;
  int grow = bm + rr;
  if (grow < M) {
    const ushort4* sp = (const ushort4*)&stage[rr * SSTR + c0];
    ushort4* gp = (ushort4*)&outh[(size_t)grow * H + n0 + c0];
    #pragma unroll
    for (int q = 0; q < 16; q++) gp[q] = sp[q];
  }
}

// ---------------- dual GEMM v5: 64-row m-tiles, LDB=76 conflict-free ----------------
#define DTM 64
#define SSTR2 132

__global__ __launch_bounds__(256) void gemm_dual3_kernel(
    const u16* __restrict__ A, const u16* __restrict__ Wlb, const u16* __restrict__ Wrb,
    const float* __restrict__ biasL, const float* __restrict__ biasR,
    u16* __restrict__ outL, u16* __restrict__ outR, int M)
{
  __shared__ u16 As[DTM * LDB];
  __shared__ u16 Bs[128 * LDB];
  int tid = threadIdx.x;
  int lane = tid & 63;
  int wave = tid >> 6;
  int wn = wave * 32;
  int nt = blockIdx.x;
  int bm = blockIdx.y * DTM;
  const u16* W = (nt < 2) ? Wlb : Wrb;
  const float* bias = (nt < 2) ? biasL : biasR;
  u16* outp = (nt < 2) ? outL : outR;
  int n0 = (nt & 1) * 128;
  int mrow = lane & 15;
  int q8 = (lane >> 4) * 8;
  int ccol = lane & 15;
  int crow4 = (lane >> 4) * 4;
  int lr = tid >> 3;
  int lc = (tid & 7) * 8;

  floatx4 zero4 = {0.f, 0.f, 0.f, 0.f};
  floatx4 acc[4][2];
  #pragma unroll
  for (int i = 0; i < 4; i++) {
    acc[i][0] = zero4;
    acc[i][1] = zero4;
  }

  for (int k0 = 0; k0 < H; k0 += 64) {
    __syncthreads();
    #pragma unroll
    for (int p = 0; p < 2; p++) {
      int row = lr + p * 32;
      int gr = bm + row;
      uint4 av = {0, 0, 0, 0};
      if (gr < M) av = *(const uint4*)&A[(size_t)gr * H + k0 + lc];
      *(uint4*)&As[row * LDB + lc] = av;
    }
    #pragma unroll
    for (int p = 0; p < 4; p++) {
      int row = lr + p * 32;
      uint4 bv = *(const uint4*)&W[(size_t)(n0 + row) * H + k0 + lc];
      *(uint4*)&Bs[row * LDB + lc] = bv;
    }
    __syncthreads();
    #pragma unroll
    for (int h = 0; h < 2; h++) {
      half8 af[4], bf[2];
      #pragma unroll
      for (int i = 0; i < 4; i++)
        af[i] = *(const half8*)&As[(i * 16 + mrow) * LDB + h * 32 + q8];
      #pragma unroll
      for (int j = 0; j < 2; j++)
        bf[j] = *(const half8*)&Bs[(wn + j * 16 + mrow) * LDB + h * 32 + q8];
      #pragma unroll
      for (int i = 0; i < 4; i++)
        #pragma unroll
        for (int j = 0; j < 2; j++)
          acc[i][j] = __builtin_amdgcn_mfma_f32_16x16x32_f16(af[i], bf[j], acc[i][j], 0, 0, 0);
    }
  }

  __syncthreads();
  u16* stage = Bs;
  #pragma unroll
  for (int j = 0; j < 2; j++) {
    float bv = bias[n0 + wn + j * 16 + ccol];
    #pragma unroll
    for (int i = 0; i < 4; i++) {
      #pragma unroll
      for (int r = 0; r < 4; r++) {
        int row = i * 16 + crow4 + r;
        stage[row * SSTR2 + wn + j * 16 + ccol] = f2h(acc[i][j][r] + bv);
      }
    }
  }
  __syncthreads();
  #pragma unroll
  for (int pass = 0; pass < 4; pass++) {
    int row = pass * 16 + (tid >> 4);
    int cu = (tid & 15) * 8;
    int grow = bm + row;
    if (grow < M) {
      *(uint4*)&outp[(size_t)grow * H + n0 + cu] =
          *(const uint4*)&stage[row * SSTR2 + cu];
    }
  }
}

// ---------------- gate GEMM v2: dual3-style 64-row m-tiles, 128-col n-tile per block ----------------
__global__ __launch_bounds__(256) void gemm_gate2_kernel(
    const u16* __restrict__ A, const u16* __restrict__ W,
    const float* __restrict__ bias, const float* __restrict__ Wg2,
    float* __restrict__ gate, int M)
{
  __shared__ u16 As[DTM * LDB];
  __shared__ u16 Bs[128 * LDB];
  int tid = threadIdx.x;
  int lane = tid & 63;
  int wave = tid >> 6;
  int wn = wave * 32;
  int n0 = blockIdx.x * 128;
  int bm = blockIdx.y * DTM;
  int mrow = lane & 15;
  int q8 = (lane >> 4) * 8;
  int ccol = lane & 15;
  int crow4 = (lane >> 4) * 4;
  int lr = tid >> 3;
  int lc = (tid & 7) * 8;

  floatx4 zero4 = {0.f, 0.f, 0.f, 0.f};
  floatx4 acc[4][2];
  #pragma unroll
  for (int i = 0; i < 4; i++) {
    acc[i][0] = zero4;
    acc[i][1] = zero4;
  }

  for (int k0 = 0; k0 < H; k0 += 64) {
    __syncthreads();
    #pragma unroll
    for (int p = 0; p < 2; p++) {
      int row = lr + p * 32;
      int gr = bm + row;
      uint4 av = {0, 0, 0, 0};
      if (gr < M) av = *(const uint4*)&A[(size_t)gr * H + k0 + lc];
      *(uint4*)&As[row * LDB + lc] = av;
    }
    #pragma unroll
    for (int p = 0; p < 4; p++) {
      int row = lr + p * 32;
      uint4 bv = *(const uint4*)&W[(size_t)(n0 + row) * H + k0 + lc];
      *(uint4*)&Bs[row * LDB + lc] = bv;
    }
    __syncthreads();
    #pragma unroll
    for (int h = 0; h < 2; h++) {
      half8 af[4], bf[2];
      #pragma unroll
      for (int i = 0; i < 4; i++)
        af[i] = *(const half8*)&As[(i * 16 + mrow) * LDB + h * 32 + q8];
      #pragma unroll
      for (int j = 0; j < 2; j++)
        bf[j] = *(const half8*)&Bs[(wn + j * 16 + mrow) * LDB + h * 32 + q8];
      #pragma unroll
      for (int i = 0; i < 4; i++)
        #pragma unroll
        for (int j = 0; j < 2; j++)
          acc[i][j] = __builtin_amdgcn_mfma_f32_16x16x32_f16(af[i], bf[j], acc[i][j], 0, 0, 0);
    }
  }

  float bv[2], wv[2];
  #pragma unroll
  for (int j = 0; j < 2; j++) {
    int c = n0 + wn + j * 16 + ccol;
    bv[j] = bias[c];
    wv[j] = Wg2[c];
  }
  #pragma unroll
  for (int i = 0; i < 4; i++) {
    #pragma unroll
    for (int r = 0; r < 4; r++) {
      float p = fmaxf(acc[i][0][r] + bv[0], 0.f) * wv[0]
              + fmaxf(acc[i][1][r] + bv[1], 0.f) * wv[1];
      p += __shfl_xor(p, 1, 64);
      p += __shfl_xor(p, 2, 64);
      p += __shfl_xor(p, 4, 64);
      p += __shfl_xor(p, 8, 64);
      int row = bm + i * 16 + crow4 + r;
      if ((lane & 15) == 0 && row < M) atomicAdd(&gate[row], p);
    }
  }
}

// ---------------- fused edge softmax + aggregate + LN + residual ----------------
// v6 FINAL: lane-partitioned dual-node waves. Each 32-lane half owns ONE node
// (8 feat/lane x 32 lanes = 256 = H). Best measured: 42.6us/dispatch.
// History: v5 manual prefetch regressed (compiler already schedules loads);
// v7 4-wide regressed (occupancy 57->30%, VGPR 52). Three latency theories
// refuted -> this structure is the practical floor for the random-gather
// workload; further gains need graph reordering (algorithmic).
__global__ __launch_bounds__(256) void layer_fused_kernel(
    const u16* __restrict__ xl, const u16* __restrict__ xr,
    u16* __restrict__ xst,
    const int* __restrict__ rowp, const int* __restrict__ col,
    const float* __restrict__ att, const float* __restrict__ bias_c,
    const float* __restrict__ ln_g, const float* __restrict__ ln_b)
{
  int lane = threadIdx.x & 63;
  int wid = blockIdx.x * 4 + (threadIdx.x >> 6);   // wave id, < N_NODES/2
  int half = lane >> 5;
  int v = wid * 2 + half;                          // node per half (always < N_NODES)
  int f8 = (lane & 31) << 3;                       // 8 features per lane

  float4 attA = *(const float4*)&att[f8];
  float4 attB = *(const float4*)&att[f8 + 4];
  h2 att0, att1, att2, att3;
  att0[0] = (_Float16)attA.x; att0[1] = (_Float16)attA.y;
  att1[0] = (_Float16)attA.z; att1[1] = (_Float16)attA.w;
  att2[0] = (_Float16)attB.x; att2[1] = (_Float16)attB.y;
  att3[0] = (_Float16)attB.z; att3[1] = (_Float16)attB.w;
  h2 nsl; nsl[0] = (_Float16)NEG_SLOPE; nsl[1] = (_Float16)NEG_SLOPE;

  size_t rowbase = (size_t)v * H + f8;
  int beg = rowp[v], end = rowp[v + 1];
  uint4 xru = *(const uint4*)&xr[rowbase];
  uint4 su  = *(const uint4*)&xl[rowbase];
  uint4 xres = *(const uint4*)&xst[rowbase];

  h2 xr0 = u2h2(xru.x), xr1 = u2h2(xru.y), xr2 = u2h2(xru.z), xr3 = u2h2(xru.w);
  h2 s0 = u2h2(su.x), s1 = u2h2(su.y), s2 = u2h2(su.z), s3 = u2h2(su.w);

  // self edge (first in row): anchor m, weight exp(0)=1 (5-stage half reduce)
  float m;
  {
    h2 t; float pe = 0.f;
    t = s0 + xr0; t = __builtin_elementwise_max(t, t * nsl); pe = fdot2f(t, att0, pe);
    t = s1 + xr1; t = __builtin_elementwise_max(t, t * nsl); pe = fdot2f(t, att1, pe);
    t = s2 + xr2; t = __builtin_elementwise_max(t, t * nsl); pe = fdot2f(t, att2, pe);
    t = s3 + xr3; t = __builtin_elementwise_max(t, t * nsl); pe = fdot2f(t, att3, pe);
    m = half_reduce_sum(pe);
  }
  float d = 1.0f;
  float o0 = (float)s0[0], o1 = (float)s0[1];
  float o2 = (float)s1[0], o3 = (float)s1[1];
  float o4 = (float)s2[0], o5 = (float)s2[1];
  float o6 = (float)s3[0], o7 = (float)s3[1];

  // edge loop: 2 edges per half per iteration; trip count = max over both halves
  int p = beg + 1;
  int rem = end - p;                         // real edges for this half's node
  int it_half = (rem + 1) >> 1;              // ceil(rem/2)
  int it_other = __shfl_xor(it_half, 32, 64);
  int iters = it_half > it_other ? it_half : it_other;

  for (int i = 0; i < iters; i++) {
    bool e0 = p < end;
    bool e1 = p + 1 < end;
    int ua = col[e0 ? p : beg];              // clamp to self row (L1-hot, w=0)
    int ub = col[e1 ? p + 1 : beg];
    uint4 A = *(const uint4*)&xl[(size_t)ua * H + f8];
    uint4 B = *(const uint4*)&xl[(size_t)ub * H + f8];
    h2 a0 = u2h2(A.x), a1 = u2h2(A.y), a2 = u2h2(A.z), a3 = u2h2(A.w);
    h2 b0 = u2h2(B.x), b1 = u2h2(B.y), b2 = u2h2(B.z), b3 = u2h2(B.w);
    float pa = 0.f, pb = 0.f;
    {
      h2 t;
      t = a0 + xr0; t = __builtin_elementwise_max(t, t * nsl); pa = fdot2f(t, att0, pa);
      t = b0 + xr0; t = __builtin_elementwise_max(t, t * nsl); pb = fdot2f(t, att0, pb);
      t = a1 + xr1; t = __builtin_elementwise_max(t, t * nsl); pa = fdot2f(t, att1, pa);
      t = b1 + xr1; t = __builtin_elementwise_max(t, t * nsl); pb = fdot2f(t, att1, pb);
      t = a2 + xr2; t = __builtin_elementwise_max(t, t * nsl); pa = fdot2f(t, att2, pa);
      t = b2 + xr2; t = __builtin_elementwise_max(t, t * nsl); pb = fdot2f(t, att2, pb);
      t = a3 + xr3; t = __builtin_elementwise_max(t, t * nsl); pa = fdot2f(t, att3, pa);
      t = b3 + xr3; t = __builtin_elementwise_max(t, t * nsl); pb = fdot2f(t, att3, pb);
    }
    #pragma unroll
    for (int off = 1; off <= 16; off <<= 1) {
      pa += __shfl_xor(pa, off, 64);
      pb += __shfl_xor(pb, off, 64);
    }
    float wa = e0 ? __expf(pa - m) : 0.f;
    float wb = e1 ? __expf(pb - m) : 0.f;
    d += wa + wb;
    o0 = fmaf(wa, (float)a0[0], fmaf(wb, (float)b0[0], o0));
    o1 = fmaf(wa, (float)a0[1], fmaf(wb, (float)b0[1], o1));
    o2 = fmaf(wa, (float)a1[0], fmaf(wb, (float)b1[0], o2));
    o3 = fmaf(wa, (float)a1[1], fmaf(wb, (float)b1[1], o3));
    o4 = fmaf(wa, (float)a2[0], fmaf(wb, (float)b2[0], o4));
    o5 = fmaf(wa, (float)a2[1], fmaf(wb, (float)b2[1], o5));
    o6 = fmaf(wa, (float)a3[0], fmaf(wb, (float)b3[0], o6));
    o7 = fmaf(wa, (float)a3[1], fmaf(wb, (float)b3[1], o7));
    p += 2;
  }

  float invd = 1.0f / d;
  float4 bcA = *(const float4*)&bias_c[f8];
  float4 bcB = *(const float4*)&bias_c[f8 + 4];
  o0 = o0 * invd + bcA.x; o1 = o1 * invd + bcA.y;
  o2 = o2 * invd + bcA.z; o3 = o3 * invd + bcA.w;
  o4 = o4 * invd + bcB.x; o5 = o5 * invd + bcB.y;
  o6 = o6 * invd + bcB.z; o7 = o7 * invd + bcB.w;

  // LN per half (each feature counted once -> exact 1/H)
  float s = ((o0 + o1) + (o2 + o3)) + ((o4 + o5) + (o6 + o7));
  s = half_reduce_sum(s);
  float mean = s * (1.0f / H);
  float c0 = o0 - mean, c1 = o1 - mean, c2 = o2 - mean, c3 = o3 - mean;
  float c4 = o4 - mean, c5 = o5 - mean, c6 = o6 - mean, c7 = o7 - mean;
  float sq = ((c0 * c0 + c1 * c1) + (c2 * c2 + c3 * c3))
           + ((c4 * c4 + c5 * c5) + (c6 * c6 + c7 * c7));
  sq = half_reduce_sum(sq);
  float rstd = rsqrtf(sq * (1.0f / H) + LN_EPS);

  float4 gA = *(const float4*)&ln_g[f8];
  float4 gB = *(const float4*)&ln_g[f8 + 4];
  float4 bA = *(const float4*)&ln_b[f8];
  float4 bB = *(const float4*)&ln_b[f8 + 4];
  h2 r0 = u2h2(xres.x), r1 = u2h2(xres.y), r2 = u2h2(xres.z), r3 = u2h2(xres.w);
  float y0 = fmaxf(fmaf(c0 * rstd, gA.x, bA.x), 0.f) + (float)r0[0];
  float y1 = fmaxf(fmaf(c1 * rstd, gA.y, bA.y), 0.f) + (float)r0[1];
  float y2 = fmaxf(fmaf(c2 * rstd, gA.z, bA.z), 0.f) + (float)r1[0];
  float y3 = fmaxf(fmaf(c3 * rstd, gA.w, bA.w), 0.f) + (float)r1[1];
  float y4 = fmaxf(fmaf(c4 * rstd, gB.x, bB.x), 0.f) + (float)r2[0];
  float y5 = fmaxf(fmaf(c5 * rstd, gB.y, bB.y), 0.f) + (float)r2[1];
  float y6 = fmaxf(fmaf(c6 * rstd, gB.z, bB.z), 0.f) + (float)r3[0];
  float y7 = fmaxf(fmaf(c7 * rstd, gB.w, bB.w), 0.f) + (float)r3[1];
  uint4 outv;
  outv.x = (unsigned)f2h(y0) | ((unsigned)f2h(y1) << 16);
  outv.y = (unsigned)f2h(y2) | ((unsigned)f2h(y3) << 16);
  outv.z = (unsigned)f2h(y4) | ((unsigned)f2h(y5) << 16);
  outv.w = (unsigned)f2h(y6) | ((unsigned)f2h(y7) << 16);
  *(uint4*)&xst[rowbase] = outv;
}

// ---------------- pooling: per-graph softmax stats (+ pooled zero) ----------------
__global__ __launch_bounds__(256) void pool_prep_kernel(
    const float* __restrict__ gate, const int* __restrict__ gstart,
    const int* __restrict__ gend, float* __restrict__ gmax, float* __restrict__ gdinv,
    float* __restrict__ pooled)
{
  __shared__ float red[256];
  int g = blockIdx.x, tid = threadIdx.x;
  pooled[(size_t)g * H + tid] = 0.f;
  int s = gstart[g], e = gend[g];
  float lm = -INFINITY;
  for (int i = s + tid; i < e; i += 256) lm = fmaxf(lm, gate[i]);
  red[tid] = lm;
  __syncthreads();
  for (int off = 128; off; off >>= 1) {
    if (tid < off) red[tid] = fmaxf(red[tid], red[tid + off]);
    __syncthreads();
  }
  float m = red[0];
  __syncthreads();
  float lsum = 0.0f;
  for (int i = s + tid; i < e; i += 256) lsum += __expf(gate[i] - m);
  red[tid] = lsum;
  __syncthreads();
  for (int off = 128; off; off >>= 1) {
    if (tid < off) red[tid] += red[tid + off];
    __syncthreads();
  }
  if (tid == 0) {
    gmax[g] = m;
    gdinv[g] = (s < e) ? 1.0f / red[0] : 0.0f;
  }
}

// ---------------- pooling: weighted accumulate (64 nodes per block, fp16 x) ----------------
__global__ __launch_bounds__(256) void pool_accum_kernel(
    const float* __restrict__ gate, const u16* __restrict__ xh,
    const int* __restrict__ batch, const float* __restrict__ gmax,
    const float* __restrict__ gdinv, float* __restrict__ pooled)
{
  __shared__ float wl[64];
  __shared__ int gl[64];
  int b0 = blockIdx.x * 64;
  int tid = threadIdx.x;
  if (tid < 64) {
    int v = b0 + tid;
    if (v < N_NODES) {
      int g = batch[v];
      gl[tid] = g;
      wl[tid] = __expf(gate[v] - gmax[g]) * gdinv[g];
    } else {
      gl[tid] = -1;
      wl[tid] = 0.f;
    }
  }
  __syncthreads();
  int cnt = min(64, N_NODES - b0);
  float acc = 0.f;
  int cur = gl[0];
  for (int j = 0; j < cnt; j++) {
    int g = gl[j];
    if (g != cur) {
      atomicAdd(&pooled[(size_t)cur * H + tid], acc);
      acc = 0.f;
      cur = g;
    }
    acc += wl[j] * h2f(xh[(size_t)(b0 + j) * H + tid]);
  }
  if (cur >= 0) atomicAdd(&pooled[(size_t)cur * H + tid], acc);
}

// ---------------- fused head: pooled -> z -> {cls, r1} -> residual ----------------
__global__ __launch_bounds__(256) void head_kernel(
    const float* __restrict__ pooled,
    const float* __restrict__ Ws, const float* __restrict__ bs,
    const float* __restrict__ Wc, const float* __restrict__ bc,
    const float* __restrict__ Wr1, const float* __restrict__ br1,
    const float* __restrict__ Wr2, const float* __restrict__ br2,
    float* __restrict__ out)
{
  __shared__ float psh[256];
  __shared__ float zsh[256];
  __shared__ float r1sh[128];
  int g = blockIdx.x, tid = threadIdx.x;
  psh[tid] = pooled[(size_t)g * H + tid];
  __syncthreads();
  {
    float acc = bs[tid];
    const float4* wr = (const float4*)&Ws[(size_t)tid * H];
    for (int k4 = 0; k4 < H / 4; k4++) {
      float4 wv = wr[k4];
      float4 av = *(const float4*)&psh[k4 * 4];
      acc += av.x * wv.x + av.y * wv.y + av.z * wv.z + av.w * wv.w;
    }
    zsh[tid] = fmaxf(acc, 0.f);
  }
  __syncthreads();
  if (tid < NB) {
    float acc = bc[tid];
    const float4* wr = (const float4*)&Wc[(size_t)tid * H];
    for (int k4 = 0; k4 < H / 4; k4++) {
      float4 wv = wr[k4];
      float4 av = *(const float4*)&zsh[k4 * 4];
      acc += av.x * wv.x + av.y * wv.y + av.z * wv.z + av.w * wv.w;
    }
    out[(size_t)g * NB + tid] = acc;
  }
  if (tid < 128) {
    float acc = br1[tid];
    const float4* wr = (const float4*)&Wr1[(size_t)tid * H];
    for (int k4 = 0; k4 < H / 4; k4++) {
      float4 wv = wr[k4];
      float4 av = *(const float4*)&zsh[k4 * 4];
      acc += av.x * wv.x + av.y * wv.y + av.z * wv.z + av.w * wv.w;
    }
    r1sh[tid] = fmaxf(acc, 0.f);
  }
  __syncthreads();
  if (tid < 64) {
    float s2 = r1sh[tid] * Wr2[tid] + r1sh[tid + 64] * Wr2[tid + 64];
    s2 = wave_reduce_sum(s2);
    if (tid == 0) out[(size_t)NGRAPH * NB + g] = tanhf(s2 + br2[0]);
  }
}

// ---------------- launcher ----------------
extern "C" void kernel_launch(void* const* d_in, const int* in_sizes, int n_in,
                              void* d_out, int out_size, void* d_ws, size_t ws_size,
                              hipStream_t stream) {
  const float* x_in   = (const float*)d_in[0];
  const int*   eidx   = (const int*)d_in[1];
  const int*   batch  = (const int*)d_in[2];
  const float* W_in   = (const float*)d_in[3];
  const float* b_in   = (const float*)d_in[4];
  const float* Wl     = (const float*)d_in[5];
  const float* bl     = (const float*)d_in[6];
  const float* Wr     = (const float*)d_in[7];
  const float* br     = (const float*)d_in[8];
  const float* att    = (const float*)d_in[9];
  const float* bias_c = (const float*)d_in[10];
  const float* ln_g   = (const float*)d_in[11];
  const float* ln_b   = (const float*)d_in[12];
  const float* Wg1    = (const float*)d_in[13];
  const float* bg1    = (const float*)d_in[14];
  const float* Wg2    = (const float*)d_in[15];
  const float* bg2    = (const float*)d_in[16];
  const float* Ws     = (const float*)d_in[17];
  const float* bs     = (const float*)d_in[18];
  const float* Wc     = (const float*)d_in[19];
  const float* bc     = (const float*)d_in[20];
  const float* Wr1    = (const float*)d_in[21];
  const float* br1    = (const float*)d_in[22];
  const float* Wr2    = (const float*)d_in[23];
  const float* br2    = (const float*)d_in[24];
  float* out = (float*)d_out;

  char* w = (char*)d_ws;
  u16* x_h    = (u16*)w;    w += sizeof(u16) * (size_t)N_NODES * H;
  u16* xl_h   = (u16*)w;    w += sizeof(u16) * (size_t)N_NODES * H;
  u16* xr_h   = (u16*)w;    w += sizeof(u16) * (size_t)N_NODES * H;
  u16* wl_h   = (u16*)w;    w += sizeof(u16) * (size_t)LAYERS * H * H;
  u16* wr_h   = (u16*)w;    w += sizeof(u16) * (size_t)LAYERS * H * H;
  u16* wg1_h  = (u16*)w;    w += sizeof(u16) * (size_t)H * H;
  float* pooled = (float*)w; w += sizeof(float) * NGRAPH * H;
  float* gate = (float*)w;  w += sizeof(float) * N_NODES;
  float* gmax = (float*)w;  w += sizeof(float) * NGRAPH;
  float* gdinv= (float*)w;  w += sizeof(float) * NGRAPH;
  int* cnt    = (int*)w;    w += sizeof(int) * N_NODES;
  int* rowp   = (int*)w;    w += sizeof(int) * (N_NODES + 1);
  int* col    = (int*)w;    w += sizeof(int) * EE;
  int* partial= (int*)w;    w += sizeof(int) * N_NODES;
  int* bsums  = (int*)w;    w += sizeof(int) * 256;
  int* gstart = (int*)w;    w += sizeof(int) * NGRAPH;
  int* gend   = (int*)w;    w += sizeof(int) * NGRAPH;
  (void)ws_size; (void)n_in; (void)in_sizes; (void)out_size;

  const int* src = eidx;
  const int* dst = eidx + N_EDGES;
  int nblkN = (N_NODES + 255) / 256;
  int nblkE = (N_EDGES + 255) / 256;
  int mtiles = (N_NODES + GTM - 1) / GTM;
  int mtiles2 = (N_NODES + DTM - 1) / DTM;

  // CSR build + gate/bounds init (merged), self-loop entry written during scan_write
  init_kernel<<<nblkN, 256, 0, stream>>>(cnt, gate, bg2, batch, gstart, gend);
  count_edges_kernel<<<nblkE, 256, 0, stream>>>(dst, cnt);
  scan_blocks_kernel<<<nblkN, 256, 0, stream>>>(cnt, partial, bsums, N_NODES);
  scan_sums_kernel<<<1, 256, 0, stream>>>(bsums, nblkN);
  scan_write_kernel<<<nblkN, 256, 0, stream>>>(partial, bsums, cnt, rowp, col, cnt, N_NODES);
  fill_edges_kernel<<<nblkE, 256, 0, stream>>>(src, dst, cnt, col);

  // weight casts (x_in cast fused into proj)
  {
    int maxn4 = LAYERS * H * H / 4;
    dim3 gcast((maxn4 + 255) / 256, 3);
    cast_weights_kernel<<<gcast, 256, 0, stream>>>(Wg1, Wl, Wr, wg1_h, wl_h, wr_h);
  }

  // input projection (fp32 inputs, fused cast) -> x_h
  dim3 gproj(2, mtiles);
  gemm_proj_kernel<<<gproj, 256, 0, stream>>>(x_in, W_in, b_in, x_h, N_NODES);

  // v6 layer_fused: one wave serves 2 nodes -> 25000 waves, 6250 blocks
  int nblkV = (N_NODES / 2 + 3) / 4;
  dim3 gdual(4, mtiles2);
  for (int l = 0; l < LAYERS; l++) {
    gemm_dual3_kernel<<<gdual, 256, 0, stream>>>(x_h,
        wl_h + (size_t)l * H * H, wr_h + (size_t)l * H * H,
        bl + l * H, br + l * H, xl_h, xr_h, N_NODES);
    layer_fused_kernel<<<nblkV, 256, 0, stream>>>(xl_h, xr_h, x_h, rowp, col,
        att + l * H, bias_c + l * H, ln_g + l * H, ln_b + l * H);
  }

  // gate (fused GEMM + row-dot); gate pre-initialized by init_kernel
  dim3 ggate(2, mtiles2);
  gemm_gate2_kernel<<<ggate, 256, 0, stream>>>(x_h, wg1_h, bg1, Wg2, gate, N_NODES);

  // pooling
  pool_prep_kernel<<<NGRAPH, 256, 0, stream>>>(gate, gstart, gend, gmax, gdinv, pooled);
  pool_accum_kernel<<<(N_NODES + 63) / 64, 256, 0, stream>>>(gate, x_h, batch, gmax, gdinv, pooled);

  // fused heads
  head_kernel<<<NGRAPH, 256, 0, stream>>>(pooled, Ws, bs, Wc, bc, Wr1, br1, Wr2, br2, out);
}